// Round 5
// baseline (299.354 us; speedup 1.0000x reference)
//
#include <hip/hip_runtime.h>
#include <stdint.h>

// ---------------------------------------------------------------------------
// BailingMoE block: T=1024, H=1024, E=16, top-4, I=512 routed, Is=1024 shared
// R12: staging-throughput model (time = staged_bytes / f(waves_in_flight)):
// keep R9's minimal staged bytes (packed bf16, 128x128 tiles) but at R8-class
// occupancy: 2-buffer LDS = 32KB -> 5 blocks/CU, 20 waves/CU, m97-style
// pipeline (stage next at top, single vmcnt(0) barrier per step).
// combine fused into phase2 via atomicAdd (out zeroed in init; phase1 already
// applies routing weights). Shared expert = z0 (longest blocks first).
// ---------------------------------------------------------------------------

typedef __attribute__((ext_vector_type(8))) unsigned short ushort8;
typedef __attribute__((ext_vector_type(4))) float f32x4;
typedef __attribute__((ext_vector_type(8))) __bf16 bf16x8;

#define T_TOK 1024
#define HID   1024
#define NEXP  16
#define TOPK  4
#define MINTER 512
#define SINTER 1024

constexpr size_t WGU_E = 32 * 1024 * 32;   // per-expert gate/up panels
constexpr size_t WD_E  = 16 * 1024 * 32;   // per-expert down panels

constexpr size_t OFF_COUNTS = 0;
constexpr size_t OFF_LIST   = 1024;
constexpr size_t OFF_WT     = OFF_LIST  + 65536;
constexpr size_t OFF_XB     = OFF_WT    + 65536;               // bf16 [1024][1024]
constexpr size_t OFF_HR     = OFF_XB    + 2097152;             // bf16 [16][4096][32]
constexpr size_t OFF_HS     = OFF_HR    + 4194304;             // bf16 [32][1024][32]
constexpr size_t OFF_WGU    = OFF_HS    + 2097152;             // bf16 [16]xWGU_E
constexpr size_t OFF_WD     = OFF_WGU   + 33554432;            // bf16 [16]xWD_E
constexpr size_t OFF_WSGU   = OFF_WD    + 16777216;            // bf16 [32][2048][32]
constexpr size_t OFF_WSD    = OFF_WSGU  + 4194304;             // bf16 [32][1024][32]

__device__ __forceinline__ unsigned short f2bf(float f) {
  union { float f; uint32_t u; } v; v.f = f;
  uint32_t r = (v.u + 0x7FFFu + ((v.u >> 16) & 1u)) >> 16;
  return (unsigned short)r;
}
__device__ __forceinline__ bf16x8 as_bf16x8(ushort8 s) {
  union { ushort8 s; bf16x8 b; } u; u.s = s; return u.b;
}
__device__ __forceinline__ float silu(float g) { return g / (1.f + __expf(-g)); }

__device__ __forceinline__ void glds16(const unsigned short* g, unsigned short* l) {
  __builtin_amdgcn_global_load_lds(
      (const __attribute__((address_space(1))) unsigned int*)g,
      (__attribute__((address_space(3))) unsigned int*)l, 16, 0, 0);
}

// m97-style single barrier per K-step: next stage's glds were issued at the
// top of the step; drain everything + this wave's ds_reads, then barrier.
// Exposed stage latency is covered by 20 waves/CU of TLP.
#define PIPE_BARRIER0() asm volatile("s_waitcnt vmcnt(0) lgkmcnt(0)\ns_barrier" ::: "memory")

// -------------------- init: zero expert counts + out -----------------------
__global__ __launch_bounds__(256) void init_kernel(int* counts, float* out) {
  if (blockIdx.x == 0 && threadIdx.x < NEXP) counts[threadIdx.x] = 0;
  const size_t t = (size_t)blockIdx.x * 256 + threadIdx.x;
  *(float4*)(out + t * 4) = (float4){0.f, 0.f, 0.f, 0.f};
}

// ------------- router (fp32, one wave/token) + fused x->bf16 write ---------
__global__ __launch_bounds__(64) void router_kernel(
    const float* __restrict__ x, const float* __restrict__ rw,
    int* counts, int* list, float* wt,
    unsigned short* __restrict__ Xb) {
  const int t = blockIdx.x, l = threadIdx.x;
  float xv[16];
#pragma unroll
  for (int j = 0; j < 16; j++) xv[j] = x[t * HID + j * 64 + l];
#pragma unroll
  for (int j = 0; j < 16; j++) Xb[t * HID + j * 64 + l] = f2bf(xv[j]);
  float p[NEXP];
#pragma unroll
  for (int e = 0; e < NEXP; e++) {
    float s = 0.f;
#pragma unroll
    for (int j = 0; j < 16; j++) s += xv[j] * rw[e * HID + j * 64 + l];
#pragma unroll
    for (int off = 32; off > 0; off >>= 1) s += __shfl_xor(s, off);
    p[e] = s;
  }
  float mx = p[0];
#pragma unroll
  for (int e = 1; e < NEXP; e++) mx = fmaxf(mx, p[e]);
  int idx[TOPK]; float w4[TOPK]; float wsum = 0.f; unsigned used = 0u;
#pragma unroll
  for (int k = 0; k < TOPK; k++) {
    float bv = -1e30f; int bi = 0;
#pragma unroll
    for (int e = 0; e < NEXP; e++)
      if (!((used >> e) & 1u) && p[e] > bv) { bv = p[e]; bi = e; }
    used |= 1u << bi;
    idx[k] = bi;
    w4[k] = __expf(p[bi] - mx);
    wsum += w4[k];
  }
  const float inv = 1.f / wsum;
  if (l < TOPK) {
    const int e = idx[l];
    const int pos = atomicAdd(&counts[e], 1);
    list[e * 1024 + pos] = t;
    wt[e * 1024 + pos]   = w4[l] * inv;
  }
}

// -------- pack_all: fp32 [K][N] weights -> bf16 k-panels [K/32][Nj][32] ----
// Interleaved (gate/up): packed j for col c = 32*(c>>4)+(c&15) (+16 for up).
__global__ __launch_bounds__(256) void pack_all_kernel(
    const float* __restrict__ Wg, const float* __restrict__ Wu,
    const float* __restrict__ Wd, const float* __restrict__ Wsgu,
    const float* __restrict__ Wsd,
    unsigned short* __restrict__ WGUp, unsigned short* __restrict__ WDp,
    unsigned short* __restrict__ WSGUp, unsigned short* __restrict__ WSDp) {
  const int bid = blockIdx.x;
  const float* src; unsigned short* dst; int C, Nj, kp0, r0, c0, jbase, ilv;
  if (bid < 2048) {                      // Wg: [16][1024][512]
    const int e = bid >> 7, loc = bid & 127, kt = loc >> 3, nt = loc & 7;
    src = Wg + (size_t)e * HID * MINTER; dst = WGUp + (size_t)e * WGU_E;
    C = MINTER; Nj = 1024; kp0 = 2 * kt; r0 = 64 * kt; c0 = 64 * nt;
    jbase = 128 * nt; ilv = 1;
  } else if (bid < 4096) {               // Wu
    const int e = (bid - 2048) >> 7, loc = bid & 127, kt = loc >> 3, nt = loc & 7;
    src = Wu + (size_t)e * HID * MINTER; dst = WGUp + (size_t)e * WGU_E;
    C = MINTER; Nj = 1024; kp0 = 2 * kt; r0 = 64 * kt; c0 = 64 * nt;
    jbase = 128 * nt + 16; ilv = 1;
  } else if (bid < 6144) {               // Wd: [16][512][1024]
    const int e = (bid - 4096) >> 7, loc = bid & 127, kt = loc >> 4, nt = loc & 15;
    src = Wd + (size_t)e * MINTER * HID; dst = WDp + (size_t)e * WD_E;
    C = HID; Nj = 1024; kp0 = 2 * kt; r0 = 64 * kt; c0 = 64 * nt;
    jbase = 64 * nt; ilv = 0;
  } else if (bid < 6656) {               // Wsgu: [1024][2048]
    const int loc = bid - 6144, kt = loc >> 5, nt = loc & 31;
    src = Wsgu; dst = WSGUp;
    C = 2048; Nj = 2048; kp0 = 2 * kt; r0 = 64 * kt; c0 = 64 * nt;
    const int isU = (nt >= 16), ntc = nt & 15;
    jbase = 128 * ntc + 16 * isU; ilv = 1;
  } else {                               // Wsd: [1024][1024]
    const int loc = bid - 6656, kt = loc >> 4, nt = loc & 15;
    src = Wsd; dst = WSDp;
    C = HID; Nj = 1024; kp0 = 2 * kt; r0 = 64 * kt; c0 = 64 * nt;
    jbase = 64 * nt; ilv = 0;
  }
  __shared__ float tile[64][65];
  const int t = threadIdx.x;
  {
    const int r = t >> 4, c4 = (t & 15) * 4;
#pragma unroll
    for (int p = 0; p < 4; p++) {
      const int rr = p * 16 + r;
      const float4 v = *(const float4*)(src + (size_t)(r0 + rr) * C + c0 + c4);
      tile[rr][c4 + 0] = v.x; tile[rr][c4 + 1] = v.y;
      tile[rr][c4 + 2] = v.z; tile[rr][c4 + 3] = v.w;
    }
  }
  __syncthreads();
  {
    const int n = t >> 2, k8 = (t & 3) * 8;
    const int j = jbase + (ilv ? (32 * (n >> 4) + (n & 15)) : n);
#pragma unroll
    for (int h = 0; h < 2; h++) {
      const int k = 32 * h + k8;
      union { unsigned short u[8]; ushort8 v; } pk;
#pragma unroll
      for (int i = 0; i < 8; i++) pk.u[i] = f2bf(tile[k + i][n]);
      *(ushort8*)(dst + ((size_t)(kp0 + h) * Nj + j) * 32 + k8) = pk.v;
    }
  }
}

// ---------------------------------------------------------------------------
// Phase 1: gate/up. Block 128m x 128j, 4 waves (wm=w>>1, wn=w&1), wave tile
// 64m x 64j = 4x4 frags, 16 MFMA/step, BK=32. 2-buffer LDS (32KB exactly ->
// 5 blocks/CU), m97 pipeline. z=0: shared. z>=1: routed expert z-1.
// ---------------------------------------------------------------------------
__global__ __launch_bounds__(256, 5) void phase1_kernel(
    const unsigned short* __restrict__ Xb,
    const unsigned short* __restrict__ WGUp,
    const unsigned short* __restrict__ WSGUp,
    const int* __restrict__ counts, const int* __restrict__ list,
    const float* __restrict__ wt,
    unsigned short* __restrict__ Hr,   // [16][4096][32]
    unsigned short* __restrict__ Hs) { // [32][1024][32]
  const int z = blockIdx.z, x = blockIdx.x, y = blockIdx.y;
  const bool routed = (z > 0);
  const int e = z - 1;
  int cnt = 0, base = 0;
  if (routed) {
    if (x >= 8) return;                // routed packed Nj=1024 -> 8 x-tiles
    cnt = counts[e];
    if (y * 128 >= cnt) return;
#pragma unroll
    for (int i = 0; i < NEXP; i++) base += (i < e) ? counts[i] : 0;
  }
  __shared__ __align__(16) unsigned short sA[2][128 * 32];
  __shared__ __align__(16) unsigned short sB[2][128 * 32];
  const int tid = threadIdx.x, w = tid >> 6, l = tid & 63;
  const int wm = w >> 1, wn = w & 1, m0 = y * 128;
  const int swz = ((l & 3) ^ ((l >> 3) & 3)) * 8;
  const int Nj = routed ? 1024 : 2048;

  // A staging: wave w covers sA rows [32w,32w+32) as 2 glds of 16 rows
  const unsigned short* aS[2];
#pragma unroll
  for (int ii = 0; ii < 2; ii++) {
    const int r = 32 * w + 16 * ii + (l >> 2);
    const unsigned short* row = routed
        ? Xb + (size_t)list[e * 1024 + min(m0 + r, cnt - 1)] * HID
        : Xb + (size_t)(m0 + r) * HID;
    aS[ii] = row + swz;
  }
  // B staging: wave w covers sB rows [32w,32w+32) as 2 glds of 16 rows
  const unsigned short* pan = routed ? WGUp + (size_t)e * WGU_E : WSGUp;
  const unsigned short* bS[2];
#pragma unroll
  for (int ii = 0; ii < 2; ii++)
    bS[ii] = pan + ((size_t)(x * 128 + 32 * w + 16 * ii + (l >> 2))) * 32 + swz;
  const size_t bStep = (size_t)Nj * 32;

  const int rsw = ((l >> 4) ^ (((l & 15) >> 1) & 3)) * 8;
  int aOff[4], bOff[4];
#pragma unroll
  for (int i = 0; i < 4; i++) aOff[i] = (64 * wm + 16 * i + (l & 15)) * 32 + rsw;
#pragma unroll
  for (int jt = 0; jt < 4; jt++) bOff[jt] = (64 * wn + 16 * jt + (l & 15)) * 32 + rsw;

  f32x4 acc[4][4];
#pragma unroll
  for (int i = 0; i < 4; i++)
#pragma unroll
    for (int jt = 0; jt < 4; jt++) acc[i][jt] = (f32x4){0.f, 0.f, 0.f, 0.f};

  auto stage = [&](int s, int b) {
    glds16(aS[0] + (size_t)s * 32, &sA[b][(32 * w) * 32]);
    glds16(aS[1] + (size_t)s * 32, &sA[b][(32 * w + 16) * 32]);
    glds16(bS[0] + (size_t)s * bStep, &sB[b][(32 * w) * 32]);
    glds16(bS[1] + (size_t)s * bStep, &sB[b][(32 * w + 16) * 32]);
  };

  const int steps = HID / 32;   // 32
  stage(0, 0);
  PIPE_BARRIER0();
#pragma unroll 1
  for (int s = 0; s < steps; s++) {
    const int cur = s & 1;
    if (s + 1 < steps) stage(s + 1, cur ^ 1);
    const unsigned short* A = &sA[cur][0];
    const unsigned short* B = &sB[cur][0];
    bf16x8 af[4], bfr[4];
#pragma unroll
    for (int i = 0; i < 4; i++) af[i] = as_bf16x8(*(const ushort8*)(A + aOff[i]));
#pragma unroll
    for (int jt = 0; jt < 4; jt++) bfr[jt] = as_bf16x8(*(const ushort8*)(B + bOff[jt]));
#pragma unroll
    for (int jt = 0; jt < 4; jt++)
#pragma unroll
      for (int i = 0; i < 4; i++)
        acc[i][jt] = __builtin_amdgcn_mfma_f32_16x16x32_bf16(af[i], bfr[jt], acc[i][jt], 0, 0, 0);
    PIPE_BARRIER0();
  }

  // epilogue: D col=lane&15, row=(lane>>4)*4+reg. jt pair (2p,2p+1) = (G,U)
  // for H panel (2x+wn), in-panel col 16p+(l&15).
  const int rl = (l >> 4) * 4, cl = l & 15;
  const int panel = 2 * x + wn;
#pragma unroll
  for (int i = 0; i < 4; i++)
#pragma unroll
    for (int r = 0; r < 4; r++) {
      const int grow = m0 + 64 * wm + 16 * i + rl + r;
#pragma unroll
      for (int p = 0; p < 2; p++) {
        const float g = acc[i][2 * p][r], u = acc[i][2 * p + 1][r];
        if (routed) {
          if (grow < cnt) {
            const float h = silu(g) * u * wt[e * 1024 + grow];
            Hr[((size_t)panel * 4096 + base + grow) * 32 + 16 * p + cl] = f2bf(h);
          }
        } else {
          const float h = silu(g) * u;
          Hs[((size_t)panel * 1024 + grow) * 32 + 16 * p + cl] = f2bf(h);
        }
      }
    }
}

// ---------------------------------------------------------------------------
// Phase 2: down-proj + fused combine. Block 128m x 128n, same machinery.
// Routed (z>=1): K=512, atomicAdd weighted rows into out[token].
// Shared (z==0): K=1024, atomicAdd into out[row] (out pre-zeroed by init).
// ---------------------------------------------------------------------------
__global__ __launch_bounds__(256, 5) void phase2_kernel(
    const unsigned short* __restrict__ Hr, const unsigned short* __restrict__ Hs,
    const unsigned short* __restrict__ WDp, const unsigned short* __restrict__ WSDp,
    const int* __restrict__ counts, const int* __restrict__ list,
    float* __restrict__ out) {           // fp32 [1024][1024]
  const int z = blockIdx.z, x = blockIdx.x, y = blockIdx.y;
  const bool routed = (z > 0);
  const int e = z - 1;
  int cnt = 0, base = 0, steps;
  if (routed) {
    cnt = counts[e];
    if (y * 128 >= cnt) return;
#pragma unroll
    for (int i = 0; i < NEXP; i++) base += (i < e) ? counts[i] : 0;
    steps = MINTER / 32;   // 16
  } else {
    steps = SINTER / 32;   // 32
  }
  __shared__ __align__(16) unsigned short sA[2][128 * 32];
  __shared__ __align__(16) unsigned short sB[2][128 * 32];
  const int tid = threadIdx.x, w = tid >> 6, l = tid & 63;
  const int wm = w >> 1, wn = w & 1, m0 = y * 128;
  const int swz = ((l & 3) ^ ((l >> 3) & 3)) * 8;
  const size_t aStep = (size_t)(routed ? 4096 : 1024) * 32;

  const unsigned short* aS[2];
#pragma unroll
  for (int ii = 0; ii < 2; ii++) {
    const int r = 32 * w + 16 * ii + (l >> 2);
    const int R = routed ? (base + min(m0 + r, cnt - 1)) : (m0 + r);
    aS[ii] = (routed ? Hr : Hs) + (size_t)R * 32 + swz;
  }
  const unsigned short* pan = routed ? WDp + (size_t)e * WD_E : WSDp;
  const unsigned short* bS[2];
#pragma unroll
  for (int ii = 0; ii < 2; ii++)
    bS[ii] = pan + ((size_t)(x * 128 + 32 * w + 16 * ii + (l >> 2))) * 32 + swz;
  const size_t bStep = (size_t)1024 * 32;

  const int rsw = ((l >> 4) ^ (((l & 15) >> 1) & 3)) * 8;
  int aOff[4], bOff[4];
#pragma unroll
  for (int i = 0; i < 4; i++) aOff[i] = (64 * wm + 16 * i + (l & 15)) * 32 + rsw;
#pragma unroll
  for (int jt = 0; jt < 4; jt++) bOff[jt] = (64 * wn + 16 * jt + (l & 15)) * 32 + rsw;

  f32x4 acc[4][4];
#pragma unroll
  for (int i = 0; i < 4; i++)
#pragma unroll
    for (int jt = 0; jt < 4; jt++) acc[i][jt] = (f32x4){0.f, 0.f, 0.f, 0.f};

  auto stage = [&](int s, int b) {
    glds16(aS[0] + (size_t)s * aStep, &sA[b][(32 * w) * 32]);
    glds16(aS[1] + (size_t)s * aStep, &sA[b][(32 * w + 16) * 32]);
    glds16(bS[0] + (size_t)s * bStep, &sB[b][(32 * w) * 32]);
    glds16(bS[1] + (size_t)s * bStep, &sB[b][(32 * w + 16) * 32]);
  };

  stage(0, 0);
  PIPE_BARRIER0();
#pragma unroll 1
  for (int s = 0; s < steps; s++) {
    const int cur = s & 1;
    if (s + 1 < steps) stage(s + 1, cur ^ 1);
    const unsigned short* A = &sA[cur][0];
    const unsigned short* B = &sB[cur][0];
    bf16x8 af[4], bfr[4];
#pragma unroll
    for (int i = 0; i < 4; i++) af[i] = as_bf16x8(*(const ushort8*)(A + aOff[i]));
#pragma unroll
    for (int jt = 0; jt < 4; jt++) bfr[jt] = as_bf16x8(*(const ushort8*)(B + bOff[jt]));
#pragma unroll
    for (int jt = 0; jt < 4; jt++)
#pragma unroll
      for (int i = 0; i < 4; i++)
        acc[i][jt] = __builtin_amdgcn_mfma_f32_16x16x32_bf16(af[i], bfr[jt], acc[i][jt], 0, 0, 0);
    PIPE_BARRIER0();
  }

  // fused combine: phase1 pre-weighted routed rows -> plain atomic scatter-add
  const int rl = (l >> 4) * 4, cl = l & 15;
#pragma unroll
  for (int i = 0; i < 4; i++)
#pragma unroll
    for (int r = 0; r < 4; r++) {
      const int grow = m0 + 64 * wm + 16 * i + rl + r;
      if (routed && grow >= cnt) continue;
      const int orow = routed ? list[e * 1024 + grow] : grow;
#pragma unroll
      for (int jt = 0; jt < 4; jt++) {
        const int col = 128 * x + 64 * wn + 16 * jt + cl;
        atomicAdd(&out[(size_t)orow * HID + col], acc[i][jt][r]);
      }
    }
}

// ---------------------------------------------------------------------------
extern "C" void kernel_launch(void* const* d_in, const int* in_sizes, int n_in,
                              void* d_out, int out_size, void* d_ws, size_t ws_size,
                              hipStream_t stream) {
  const float* x      = (const float*)d_in[0];
  const float* rw     = (const float*)d_in[1];
  const float* w_gate = (const float*)d_in[2];
  const float* w_up   = (const float*)d_in[3];
  const float* w_down = (const float*)d_in[4];
  const float* ws_gu  = (const float*)d_in[5];
  const float* ws_dn  = (const float*)d_in[6];
  float* out = (float*)d_out;
  char* ws = (char*)d_ws;

  int*   counts = (int*)  (ws + OFF_COUNTS);
  int*   list   = (int*)  (ws + OFF_LIST);
  float* wtbuf  = (float*)(ws + OFF_WT);
  unsigned short* Xb    = (unsigned short*)(ws + OFF_XB);
  unsigned short* Hr    = (unsigned short*)(ws + OFF_HR);
  unsigned short* Hs    = (unsigned short*)(ws + OFF_HS);
  unsigned short* WGUp  = (unsigned short*)(ws + OFF_WGU);
  unsigned short* WDp   = (unsigned short*)(ws + OFF_WD);
  unsigned short* WSGUp = (unsigned short*)(ws + OFF_WSGU);
  unsigned short* WSDp  = (unsigned short*)(ws + OFF_WSD);

  init_kernel<<<1024, 256, 0, stream>>>(counts, out);   // zeros out (4MB) + counts
  router_kernel<<<T_TOK, 64, 0, stream>>>(x, rw, counts, list, wtbuf, Xb);
  pack_all_kernel<<<6912, 256, 0, stream>>>(
      w_gate, w_up, w_down, ws_gu, ws_dn, WGUp, WDp, WSGUp, WSDp);
  phase1_kernel<<<dim3(16, 8, 17), 256, 0, stream>>>(
      Xb, WGUp, WSGUp, counts, list, wtbuf, Hr, Hs);
  phase2_kernel<<<dim3(8, 8, 17), 256, 0, stream>>>(
      Hr, Hs, WDp, WSDp, counts, list, out);
  (void)in_sizes; (void)n_in; (void)out_size; (void)ws_size;
}

// Round 6
// 247.855 us; speedup vs baseline: 1.2078x; 1.2078x over previous
//
#include <hip/hip_runtime.h>
#include <stdint.h>

// ---------------------------------------------------------------------------
// BailingMoE block: T=1024, H=1024, E=16, top-4, I=512 routed, Is=1024 shared
// R13: wave-count fix. Invariant across R7-R12: staged-LDS throughput ~2GB/s
// per wave; R9's 128x128 tiling had best staged bytes (196MB p1) but only
// 1664 waves (0.8/SIMD). Keep the tile, go 8 waves/block (wave 64x32,
// acc[4][2]=32 regs -> launch_bounds(512,4), cap 128, no spill — R12's
// regression was acc spills from (256,5)'s 102-reg cap, visible as VGPR=48 +
// WRITE_SIZE 2x). 3-buffer pipeline, counted vmcnt(2) (2 glds/wave/stage).
// combine fused into phase2 (atomicAdd, out pre-zeroed; phase1 pre-weights).
// ---------------------------------------------------------------------------

typedef __attribute__((ext_vector_type(8))) unsigned short ushort8;
typedef __attribute__((ext_vector_type(4))) float f32x4;
typedef __attribute__((ext_vector_type(8))) __bf16 bf16x8;

#define T_TOK 1024
#define HID   1024
#define NEXP  16
#define TOPK  4
#define MINTER 512
#define SINTER 1024

constexpr size_t WGU_E = 32 * 1024 * 32;   // per-expert gate/up panels
constexpr size_t WD_E  = 16 * 1024 * 32;   // per-expert down panels

constexpr size_t OFF_COUNTS = 0;
constexpr size_t OFF_LIST   = 1024;
constexpr size_t OFF_WT     = OFF_LIST  + 65536;
constexpr size_t OFF_XB     = OFF_WT    + 65536;               // bf16 [1024][1024]
constexpr size_t OFF_HR     = OFF_XB    + 2097152;             // bf16 [16][4096][32]
constexpr size_t OFF_HS     = OFF_HR    + 4194304;             // bf16 [32][1024][32]
constexpr size_t OFF_WGU    = OFF_HS    + 2097152;             // bf16 [16]xWGU_E
constexpr size_t OFF_WD     = OFF_WGU   + 33554432;            // bf16 [16]xWD_E
constexpr size_t OFF_WSGU   = OFF_WD    + 16777216;            // bf16 [32][2048][32]
constexpr size_t OFF_WSD    = OFF_WSGU  + 4194304;             // bf16 [32][1024][32]

__device__ __forceinline__ unsigned short f2bf(float f) {
  union { float f; uint32_t u; } v; v.f = f;
  uint32_t r = (v.u + 0x7FFFu + ((v.u >> 16) & 1u)) >> 16;
  return (unsigned short)r;
}
__device__ __forceinline__ bf16x8 as_bf16x8(ushort8 s) {
  union { ushort8 s; bf16x8 b; } u; u.s = s; return u.b;
}
__device__ __forceinline__ float silu(float g) { return g / (1.f + __expf(-g)); }

__device__ __forceinline__ void glds16(const unsigned short* g, unsigned short* l) {
  __builtin_amdgcn_global_load_lds(
      (const __attribute__((address_space(1))) unsigned int*)g,
      (__attribute__((address_space(3))) unsigned int*)l, 16, 0, 0);
}

// 2 glds/wave/stage, 3 buffers. vmcnt(2) drains only the OLDEST in-flight
// stage (the next stage's 2 loads stay in flight across the barrier).
// lgkmcnt(0): this wave's ds_reads of the previous step are in registers
// before any buffer can be overwritten.
#define PIPE_BARRIER2() asm volatile("s_waitcnt vmcnt(2) lgkmcnt(0)\ns_barrier" ::: "memory")
#define PIPE_BARRIER0() asm volatile("s_waitcnt vmcnt(0) lgkmcnt(0)\ns_barrier" ::: "memory")

// -------------------- init: zero expert counts + out -----------------------
__global__ __launch_bounds__(256) void init_kernel(int* counts, float* out) {
  if (blockIdx.x == 0 && threadIdx.x < NEXP) counts[threadIdx.x] = 0;
  const size_t t = (size_t)blockIdx.x * 256 + threadIdx.x;
  *(float4*)(out + t * 4) = (float4){0.f, 0.f, 0.f, 0.f};
}

// ------------- router (fp32, one wave/token) + fused x->bf16 write ---------
__global__ __launch_bounds__(64) void router_kernel(
    const float* __restrict__ x, const float* __restrict__ rw,
    int* counts, int* list, float* wt,
    unsigned short* __restrict__ Xb) {
  const int t = blockIdx.x, l = threadIdx.x;
  float xv[16];
#pragma unroll
  for (int j = 0; j < 16; j++) xv[j] = x[t * HID + j * 64 + l];
#pragma unroll
  for (int j = 0; j < 16; j++) Xb[t * HID + j * 64 + l] = f2bf(xv[j]);
  float p[NEXP];
#pragma unroll
  for (int e = 0; e < NEXP; e++) {
    float s = 0.f;
#pragma unroll
    for (int j = 0; j < 16; j++) s += xv[j] * rw[e * HID + j * 64 + l];
#pragma unroll
    for (int off = 32; off > 0; off >>= 1) s += __shfl_xor(s, off);
    p[e] = s;
  }
  float mx = p[0];
#pragma unroll
  for (int e = 1; e < NEXP; e++) mx = fmaxf(mx, p[e]);
  int idx[TOPK]; float w4[TOPK]; float wsum = 0.f; unsigned used = 0u;
#pragma unroll
  for (int k = 0; k < TOPK; k++) {
    float bv = -1e30f; int bi = 0;
#pragma unroll
    for (int e = 0; e < NEXP; e++)
      if (!((used >> e) & 1u) && p[e] > bv) { bv = p[e]; bi = e; }
    used |= 1u << bi;
    idx[k] = bi;
    w4[k] = __expf(p[bi] - mx);
    wsum += w4[k];
  }
  const float inv = 1.f / wsum;
  if (l < TOPK) {
    const int e = idx[l];
    const int pos = atomicAdd(&counts[e], 1);
    list[e * 1024 + pos] = t;
    wt[e * 1024 + pos]   = w4[l] * inv;
  }
}

// -------- pack_all: fp32 [K][N] weights -> bf16 k-panels [K/32][Nj][32] ----
// Interleaved (gate/up): packed j for col c = 32*(c>>4)+(c&15) (+16 for up).
__global__ __launch_bounds__(256) void pack_all_kernel(
    const float* __restrict__ Wg, const float* __restrict__ Wu,
    const float* __restrict__ Wd, const float* __restrict__ Wsgu,
    const float* __restrict__ Wsd,
    unsigned short* __restrict__ WGUp, unsigned short* __restrict__ WDp,
    unsigned short* __restrict__ WSGUp, unsigned short* __restrict__ WSDp) {
  const int bid = blockIdx.x;
  const float* src; unsigned short* dst; int C, Nj, kp0, r0, c0, jbase, ilv;
  if (bid < 2048) {                      // Wg: [16][1024][512]
    const int e = bid >> 7, loc = bid & 127, kt = loc >> 3, nt = loc & 7;
    src = Wg + (size_t)e * HID * MINTER; dst = WGUp + (size_t)e * WGU_E;
    C = MINTER; Nj = 1024; kp0 = 2 * kt; r0 = 64 * kt; c0 = 64 * nt;
    jbase = 128 * nt; ilv = 1;
  } else if (bid < 4096) {               // Wu
    const int e = (bid - 2048) >> 7, loc = bid & 127, kt = loc >> 3, nt = loc & 7;
    src = Wu + (size_t)e * HID * MINTER; dst = WGUp + (size_t)e * WGU_E;
    C = MINTER; Nj = 1024; kp0 = 2 * kt; r0 = 64 * kt; c0 = 64 * nt;
    jbase = 128 * nt + 16; ilv = 1;
  } else if (bid < 6144) {               // Wd: [16][512][1024]
    const int e = (bid - 4096) >> 7, loc = bid & 127, kt = loc >> 4, nt = loc & 15;
    src = Wd + (size_t)e * MINTER * HID; dst = WDp + (size_t)e * WD_E;
    C = HID; Nj = 1024; kp0 = 2 * kt; r0 = 64 * kt; c0 = 64 * nt;
    jbase = 64 * nt; ilv = 0;
  } else if (bid < 6656) {               // Wsgu: [1024][2048]
    const int loc = bid - 6144, kt = loc >> 5, nt = loc & 31;
    src = Wsgu; dst = WSGUp;
    C = 2048; Nj = 2048; kp0 = 2 * kt; r0 = 64 * kt; c0 = 64 * nt;
    const int isU = (nt >= 16), ntc = nt & 15;
    jbase = 128 * ntc + 16 * isU; ilv = 1;
  } else {                               // Wsd: [1024][1024]
    const int loc = bid - 6656, kt = loc >> 4, nt = loc & 15;
    src = Wsd; dst = WSDp;
    C = HID; Nj = 1024; kp0 = 2 * kt; r0 = 64 * kt; c0 = 64 * nt;
    jbase = 64 * nt; ilv = 0;
  }
  __shared__ float tile[64][65];
  const int t = threadIdx.x;
  {
    const int r = t >> 4, c4 = (t & 15) * 4;
#pragma unroll
    for (int p = 0; p < 4; p++) {
      const int rr = p * 16 + r;
      const float4 v = *(const float4*)(src + (size_t)(r0 + rr) * C + c0 + c4);
      tile[rr][c4 + 0] = v.x; tile[rr][c4 + 1] = v.y;
      tile[rr][c4 + 2] = v.z; tile[rr][c4 + 3] = v.w;
    }
  }
  __syncthreads();
  {
    const int n = t >> 2, k8 = (t & 3) * 8;
    const int j = jbase + (ilv ? (32 * (n >> 4) + (n & 15)) : n);
#pragma unroll
    for (int h = 0; h < 2; h++) {
      const int k = 32 * h + k8;
      union { unsigned short u[8]; ushort8 v; } pk;
#pragma unroll
      for (int i = 0; i < 8; i++) pk.u[i] = f2bf(tile[k + i][n]);
      *(ushort8*)(dst + ((size_t)(kp0 + h) * Nj + j) * 32 + k8) = pk.v;
    }
  }
}

// ---------------------------------------------------------------------------
// Phase 1: gate/up. Block 128m x 128j, 8 waves (wm=w>>2, wn=w&3), wave tile
// 64m x 32j = 4x2 frags (jt0=G, jt1=U of I-col group p=4x+wn), 8 MFMA/step,
// BK=32. 3-buffer pipeline, vmcnt(2). LDS 48KB. z=0: shared; z>=1: expert z-1.
// ---------------------------------------------------------------------------
__global__ __launch_bounds__(512, 4) void phase1_kernel(
    const unsigned short* __restrict__ Xb,
    const unsigned short* __restrict__ WGUp,
    const unsigned short* __restrict__ WSGUp,
    const int* __restrict__ counts, const int* __restrict__ list,
    const float* __restrict__ wt,
    unsigned short* __restrict__ Hr,   // [16][4096][32]
    unsigned short* __restrict__ Hs) { // [32][1024][32]
  const int z = blockIdx.z, x = blockIdx.x, y = blockIdx.y;
  const bool routed = (z > 0);
  const int e = z - 1;
  int cnt = 0, base = 0;
  if (routed) {
    if (x >= 8) return;                // routed packed Nj=1024 -> 8 x-tiles
    cnt = counts[e];
    if (y * 128 >= cnt) return;
#pragma unroll
    for (int i = 0; i < NEXP; i++) base += (i < e) ? counts[i] : 0;
  }
  __shared__ __align__(16) unsigned short sA[3][128 * 32];
  __shared__ __align__(16) unsigned short sB[3][128 * 32];
  const int tid = threadIdx.x, w = tid >> 6, l = tid & 63;
  const int wm = w >> 2, wn = w & 3, m0 = y * 128;
  const int g = l >> 4, r15 = l & 15;
  const int swz = ((l & 3) ^ ((l >> 3) & 3)) * 8;
  const int Nj = routed ? 1024 : 2048;

  // A staging: wave w covers sA rows [16w,16w+16) as 1 glds of 16 rows
  const int ar = 16 * w + (l >> 2);
  const unsigned short* aS = (routed
      ? Xb + (size_t)list[e * 1024 + min(m0 + ar, cnt - 1)] * HID
      : Xb + (size_t)(m0 + ar) * HID) + swz;
  // B staging: wave w covers sB rows [16w,16w+16) as 1 glds
  const unsigned short* pan = routed ? WGUp + (size_t)e * WGU_E : WSGUp;
  const unsigned short* bS =
      pan + ((size_t)(x * 128 + 16 * w + (l >> 2))) * 32 + swz;
  const size_t bStep = (size_t)Nj * 32;

  const int rsw = (g ^ ((r15 >> 1) & 3)) * 8;
  int aOff[4], bOff[2];
#pragma unroll
  for (int i = 0; i < 4; i++) aOff[i] = (64 * wm + 16 * i + r15) * 32 + rsw;
#pragma unroll
  for (int jt = 0; jt < 2; jt++) bOff[jt] = (32 * wn + 16 * jt + r15) * 32 + rsw;

  f32x4 acc[4][2];
#pragma unroll
  for (int i = 0; i < 4; i++)
#pragma unroll
    for (int jt = 0; jt < 2; jt++) acc[i][jt] = (f32x4){0.f, 0.f, 0.f, 0.f};

  auto stage = [&](int s, int b) {
    glds16(aS + (size_t)s * 32, &sA[b][(16 * w) * 32]);
    glds16(bS + (size_t)s * bStep, &sB[b][(16 * w) * 32]);
  };

  const int steps = HID / 32;   // 32
  stage(0, 0); stage(1, 1);
#pragma unroll 1
  for (int s = 0; s < steps; s++) {
    const int cb = s % 3;
    if (s + 2 < steps)      { PIPE_BARRIER2(); stage(s + 2, (s + 2) % 3); }
    else if (s + 1 < steps) { PIPE_BARRIER2(); }
    else                    { PIPE_BARRIER0(); }
    const unsigned short* A = &sA[cb][0];
    const unsigned short* B = &sB[cb][0];
    bf16x8 af[4], bfr[2];
#pragma unroll
    for (int i = 0; i < 4; i++) af[i] = as_bf16x8(*(const ushort8*)(A + aOff[i]));
#pragma unroll
    for (int jt = 0; jt < 2; jt++) bfr[jt] = as_bf16x8(*(const ushort8*)(B + bOff[jt]));
#pragma unroll
    for (int jt = 0; jt < 2; jt++)
#pragma unroll
      for (int i = 0; i < 4; i++)
        acc[i][jt] = __builtin_amdgcn_mfma_f32_16x16x32_bf16(af[i], bfr[jt], acc[i][jt], 0, 0, 0);
  }

  // epilogue: D col=lane&15, row=(lane>>4)*4+reg. Wave covers I-col group
  // p = 4x+wn (16 I-cols): jt=0 -> G, jt=1 -> U; I-col = 16p + r15.
  // H layout [panel=Icol/32][row][32]: panel = p>>1, in-panel col 16(p&1)+r15.
  const int rl = g * 4;
  const int p = 4 * x + wn;
  const int hcol = 16 * (p & 1) + r15;
  const size_t panel = (size_t)(p >> 1);
#pragma unroll
  for (int i = 0; i < 4; i++)
#pragma unroll
    for (int r = 0; r < 4; r++) {
      const int grow = m0 + 64 * wm + 16 * i + rl + r;
      const float gv = acc[i][0][r], uv = acc[i][1][r];
      if (routed) {
        if (grow < cnt) {
          const float h = silu(gv) * uv * wt[e * 1024 + grow];
          Hr[(panel * 4096 + base + grow) * 32 + hcol] = f2bf(h);
        }
      } else {
        const float h = silu(gv) * uv;
        Hs[(panel * 1024 + grow) * 32 + hcol] = f2bf(h);
      }
    }
}

// ---------------------------------------------------------------------------
// Phase 2: down-proj + fused combine. Block 128m x 128n, 8 waves (64m x 32n),
// same pipeline. Routed (z>=1): K=512, rows pre-weighted -> atomicAdd into
// out[token]. Shared (z==0): K=1024 -> atomicAdd into out[row].
// ---------------------------------------------------------------------------
__global__ __launch_bounds__(512, 4) void phase2_kernel(
    const unsigned short* __restrict__ Hr, const unsigned short* __restrict__ Hs,
    const unsigned short* __restrict__ WDp, const unsigned short* __restrict__ WSDp,
    const int* __restrict__ counts, const int* __restrict__ list,
    float* __restrict__ out) {           // fp32 [1024][1024]
  const int z = blockIdx.z, x = blockIdx.x, y = blockIdx.y;
  const bool routed = (z > 0);
  const int e = z - 1;
  int cnt = 0, base = 0, steps;
  if (routed) {
    cnt = counts[e];
    if (y * 128 >= cnt) return;
#pragma unroll
    for (int i = 0; i < NEXP; i++) base += (i < e) ? counts[i] : 0;
    steps = MINTER / 32;   // 16
  } else {
    steps = SINTER / 32;   // 32
  }
  __shared__ __align__(16) unsigned short sA[3][128 * 32];
  __shared__ __align__(16) unsigned short sB[3][128 * 32];
  const int tid = threadIdx.x, w = tid >> 6, l = tid & 63;
  const int wm = w >> 2, wn = w & 3, m0 = y * 128;
  const int g = l >> 4, r15 = l & 15;
  const int swz = ((l & 3) ^ ((l >> 3) & 3)) * 8;
  const size_t aStep = (size_t)(routed ? 4096 : 1024) * 32;

  const int ar = 16 * w + (l >> 2);
  const int R = routed ? (base + min(m0 + ar, cnt - 1)) : (m0 + ar);
  const unsigned short* aS = (routed ? Hr : Hs) + (size_t)R * 32 + swz;
  const unsigned short* pan = routed ? WDp + (size_t)e * WD_E : WSDp;
  const unsigned short* bS =
      pan + ((size_t)(x * 128 + 16 * w + (l >> 2))) * 32 + swz;
  const size_t bStep = (size_t)1024 * 32;

  const int rsw = (g ^ ((r15 >> 1) & 3)) * 8;
  int aOff[4], bOff[2];
#pragma unroll
  for (int i = 0; i < 4; i++) aOff[i] = (64 * wm + 16 * i + r15) * 32 + rsw;
#pragma unroll
  for (int jt = 0; jt < 2; jt++) bOff[jt] = (32 * wn + 16 * jt + r15) * 32 + rsw;

  f32x4 acc[4][2];
#pragma unroll
  for (int i = 0; i < 4; i++)
#pragma unroll
    for (int jt = 0; jt < 2; jt++) acc[i][jt] = (f32x4){0.f, 0.f, 0.f, 0.f};

  auto stage = [&](int s, int b) {
    glds16(aS + (size_t)s * aStep, &sA[b][(16 * w) * 32]);
    glds16(bS + (size_t)s * bStep, &sB[b][(16 * w) * 32]);
  };

  stage(0, 0); stage(1, 1);
#pragma unroll 1
  for (int s = 0; s < steps; s++) {
    const int cb = s % 3;
    if (s + 2 < steps)      { PIPE_BARRIER2(); stage(s + 2, (s + 2) % 3); }
    else if (s + 1 < steps) { PIPE_BARRIER2(); }
    else                    { PIPE_BARRIER0(); }
    const unsigned short* A = &sA[cb][0];
    const unsigned short* B = &sB[cb][0];
    bf16x8 af[4], bfr[2];
#pragma unroll
    for (int i = 0; i < 4; i++) af[i] = as_bf16x8(*(const ushort8*)(A + aOff[i]));
#pragma unroll
    for (int jt = 0; jt < 2; jt++) bfr[jt] = as_bf16x8(*(const ushort8*)(B + bOff[jt]));
#pragma unroll
    for (int jt = 0; jt < 2; jt++)
#pragma unroll
      for (int i = 0; i < 4; i++)
        acc[i][jt] = __builtin_amdgcn_mfma_f32_16x16x32_bf16(af[i], bfr[jt], acc[i][jt], 0, 0, 0);
  }

  // fused combine: phase1 pre-weighted routed rows -> atomic scatter-add
  const int rl = g * 4;
#pragma unroll
  for (int i = 0; i < 4; i++)
#pragma unroll
    for (int r = 0; r < 4; r++) {
      const int grow = m0 + 64 * wm + 16 * i + rl + r;
      if (routed && grow >= cnt) continue;
      const int orow = routed ? list[e * 1024 + grow] : grow;
#pragma unroll
      for (int jt = 0; jt < 2; jt++) {
        const int col = 128 * x + 32 * wn + 16 * jt + r15;
        atomicAdd(&out[(size_t)orow * HID + col], acc[i][jt][r]);
      }
    }
}

// ---------------------------------------------------------------------------
extern "C" void kernel_launch(void* const* d_in, const int* in_sizes, int n_in,
                              void* d_out, int out_size, void* d_ws, size_t ws_size,
                              hipStream_t stream) {
  const float* x      = (const float*)d_in[0];
  const float* rw     = (const float*)d_in[1];
  const float* w_gate = (const float*)d_in[2];
  const float* w_up   = (const float*)d_in[3];
  const float* w_down = (const float*)d_in[4];
  const float* ws_gu  = (const float*)d_in[5];
  const float* ws_dn  = (const float*)d_in[6];
  float* out = (float*)d_out;
  char* ws = (char*)d_ws;

  int*   counts = (int*)  (ws + OFF_COUNTS);
  int*   list   = (int*)  (ws + OFF_LIST);
  float* wtbuf  = (float*)(ws + OFF_WT);
  unsigned short* Xb    = (unsigned short*)(ws + OFF_XB);
  unsigned short* Hr    = (unsigned short*)(ws + OFF_HR);
  unsigned short* Hs    = (unsigned short*)(ws + OFF_HS);
  unsigned short* WGUp  = (unsigned short*)(ws + OFF_WGU);
  unsigned short* WDp   = (unsigned short*)(ws + OFF_WD);
  unsigned short* WSGUp = (unsigned short*)(ws + OFF_WSGU);
  unsigned short* WSDp  = (unsigned short*)(ws + OFF_WSD);

  init_kernel<<<1024, 256, 0, stream>>>(counts, out);   // zeros out (4MB) + counts
  router_kernel<<<T_TOK, 64, 0, stream>>>(x, rw, counts, list, wtbuf, Xb);
  pack_all_kernel<<<6912, 256, 0, stream>>>(
      w_gate, w_up, w_down, ws_gu, ws_dn, WGUp, WDp, WSGUp, WSDp);
  phase1_kernel<<<dim3(16, 8, 17), 512, 0, stream>>>(
      Xb, WGUp, WSGUp, counts, list, wtbuf, Hr, Hs);
  phase2_kernel<<<dim3(8, 8, 17), 512, 0, stream>>>(
      Hr, Hs, WDp, WSDp, counts, list, out);
  (void)in_sizes; (void)n_in; (void)out_size; (void)ws_size;
}